// Round 8
// baseline (169.436 us; speedup 1.0000x reference)
//
#include <hip/hip_runtime.h>

// LSTM autoencoder via bf16 MFMA, v6: 12-wave blocks, job-split for 24 waves/CU.
// B=8192, T=30, F=16, H1=64, H2=32. Grid 512 x 768 thr, BT=16, 2 blocks/CU.
// Per step phase A: 24 tile-jobs = 16 z1 + 8 z2. Waves 0..7: z1 tiles {w,w+8}
// (reads bx,bh1a,bh1b); waves 8..11: z2 tiles {2u,2u+1} (reads bh1a,bh1b,bh2).
// Phase B: waves 0..7: z4 {w,w+8} + rotating proj; waves 8..11: z3 {2u,2u+1}.
// log2e folded into weights/biases (gate g rows x 2log2e) -> raw v_exp_f32.
// aB (stride 264 u16): phA h1 dbuf p*64, h2 dbuf 128+p*32, latent 160..191;
//                      phB h4 dbuf p*64, latent 160 (preserved), h3 dbuf 192+p*32.
// LDS: xAll 16x968 (30.2KB) + aB 16x264 (8.25KB) = 38.5KB.

#define TT 30
#define FF 16
#define NT 768

typedef unsigned short u16t;
typedef __attribute__((ext_vector_type(8))) short short8;
typedef __attribute__((ext_vector_type(4))) short short4v;
typedef __attribute__((ext_vector_type(4))) float floatx4;

#define MFMA(a, b, c) __builtin_amdgcn_mfma_f32_16x16x32_bf16(a, b, c, 0, 0, 0)

#if __has_builtin(__builtin_amdgcn_exp2f)
#define EXP2(x) __builtin_amdgcn_exp2f(x)
#else
#define EXP2(x) exp2f(x)
#endif

template <int P> struct IC { static constexpr int v = P; };

__device__ __forceinline__ float rcpf(float v) { return __builtin_amdgcn_rcpf(v); }
__device__ __forceinline__ u16t f2bf(float f) {
  unsigned int u = __float_as_uint(f);
  u = (u + 0x7FFFu + ((u >> 16) & 1u)) >> 16;
  return (u16t)u;
}
__device__ __forceinline__ short8 ldFragS(const float* p, float s) {
  const float4 lo = *(const float4*)p;
  const float4 hi = *(const float4*)(p + 4);
  short8 r;
  r[0] = (short)f2bf(lo.x * s); r[1] = (short)f2bf(lo.y * s);
  r[2] = (short)f2bf(lo.z * s); r[3] = (short)f2bf(lo.w * s);
  r[4] = (short)f2bf(hi.x * s); r[5] = (short)f2bf(hi.y * s);
  r[6] = (short)f2bf(hi.z * s); r[7] = (short)f2bf(hi.w * s);
  return r;
}
// acc pre-scaled by log2e (gates i,f,o) / 2log2e (gate g). lane owns i,f,g,o of one unit.
__device__ __forceinline__ float cellUp(const floatx4 acc, float& c) {
  float iv = rcpf(1.f + EXP2(-acc[0]));
  float fv = rcpf(1.f + EXP2(-acc[1]));
  float gv = 1.f - 2.f * rcpf(1.f + EXP2(acc[2]));
  float ov = rcpf(1.f + EXP2(-acc[3]));
  c = fv * c + iv * gv;
  float th = 1.f - 2.f * rcpf(1.f + EXP2(2.885390082f * c));
  return ov * th;
}

__global__ __launch_bounds__(NT, 6) void lstm_ae_mfma6(
    const float* __restrict__ x,
    const float* __restrict__ Wih1, const float* __restrict__ Whh1, const float* __restrict__ b1,
    const float* __restrict__ Wih2, const float* __restrict__ Whh2, const float* __restrict__ b2,
    const float* __restrict__ Wih3, const float* __restrict__ Whh3, const float* __restrict__ b3,
    const float* __restrict__ Wih4, const float* __restrict__ Whh4, const float* __restrict__ b4,
    const float* __restrict__ Wout, const float* __restrict__ bout,
    float* __restrict__ out)
{
  __shared__ __align__(16) u16t xAll[16 * 968];  // x bf16, k16..31 zero-pad, stride 968
  __shared__ __align__(16) u16t aB[16 * 264];    // recurrent state, stride 264

  const int t = threadIdx.x;
  const int w = t >> 6, lane = t & 63;           // 12 waves
  const int q = lane >> 4, n = lane & 15;
  const int q8 = q * 8, n264 = n * 264, n968 = n * 968;
  const int bBase = blockIdx.x * 16;
  const int nlo = n >> 2, ngt = n & 3;
  const u16t* aRow = &aB[n264];
  const bool isZ1 = (w < 8);                     // z1/z4 waves vs z2/z3 waves
  const int u = w & 3;                           // for waves 8..11

  const float L1 = 1.442695041f, L2 = 2.885390082f;
  const float sA = (ngt == 2) ? L2 : L1;         // per-lane A-row scale (gate g doubles)

  // ================= init =================
  for (int i = t; i < 16 * 264; i += NT) aB[i] = 0;
  {
    const float* xb = x + (size_t)bBase * (TT * FF);
    for (int i4 = t; i4 < 1920; i4 += NT) {
      int e = i4 * 4;
      int b = e / 480, r = e - b * 480;
      int stp = r >> 4, f = r & 15;
      float4 v = *(const float4*)&xb[e];
      short4v s4 = { (short)f2bf(v.x), (short)f2bf(v.y), (short)f2bf(v.z), (short)f2bf(v.w) };
      *(short4v*)&xAll[b * 968 + stp * 32 + f] = s4;
    }
    for (int i = t; i < 7680; i += NT) {   // zero pads k=16..31
      int b = i / 480, r = i - b * 480;
      int stp = r >> 4, f = r & 15;
      xAll[b * 968 + stp * 32 + 16 + f] = 0;
    }
  }
  const short8 z8 = { 0, 0, 0, 0, 0, 0, 0, 0 };
  short8 wAf[2][3]; floatx4 biasA[2];            // z1 (waves 0..7) or z2 (waves 8..11)
  if (isZ1) {
#pragma unroll
    for (int tt = 0; tt < 2; ++tt) {
      int T = w + 8 * tt;
      int row = ngt * 64 + T * 4 + nlo;
      wAf[tt][0] = z8;
      if (q < 2) wAf[tt][0] = ldFragS(&Wih1[row * 16 + q8], sA);
      wAf[tt][1] = ldFragS(&Whh1[row * 64 + q8], sA);
      wAf[tt][2] = ldFragS(&Whh1[row * 64 + 32 + q8], sA);
#pragma unroll
      for (int r = 0; r < 4; ++r) biasA[tt][r] = b1[r * 64 + T * 4 + q] * (r == 2 ? L2 : L1);
    }
  } else {
#pragma unroll
    for (int tt = 0; tt < 2; ++tt) {
      int T = 2 * u + tt;
      int row = ngt * 32 + T * 4 + nlo;
      wAf[tt][0] = ldFragS(&Wih2[row * 64 + q8], sA);
      wAf[tt][1] = ldFragS(&Wih2[row * 64 + 32 + q8], sA);
      wAf[tt][2] = ldFragS(&Whh2[row * 32 + q8], sA);
#pragma unroll
      for (int r = 0; r < 4; ++r) biasA[tt][r] = b2[r * 32 + T * 4 + q] * (r == 2 ? L2 : L1);
    }
  }
  // anti-phase nudge for likely co-resident pair (i, i+256)
  if (blockIdx.x & 256) {
    __builtin_amdgcn_s_sleep(15);
    __builtin_amdgcn_s_sleep(15);
  }
  __syncthreads();

  float cA[2] = {0.f, 0.f};
  short8 bxN;

  // ---- peel: z1(0) (h1(-1)=0), z2-waves idle ----
  if (isZ1) {
    const short8 bx = *(const short8*)&xAll[n968 + q8];
#pragma unroll
    for (int tt = 0; tt < 2; ++tt) {
      floatx4 a0 = biasA[tt];
      a0 = MFMA(wAf[tt][0], bx, a0);
      aB[n264 + (w + 8 * tt) * 4 + q] = f2bf(cellUp(a0, cA[tt]));
    }
    bxN = *(const short8*)&xAll[n968 + 32 + q8];   // prefetch x(1)
  }
  __syncthreads();

  // ================= Phase A: 29 skewed regions, 1 barrier each =================
  auto stepA = [&](int st, auto pc) {
    constexpr int p = decltype(pc)::v;
    const short8 bh1a = *(const short8*)&aRow[p * 64 + q8];
    const short8 bh1b = *(const short8*)&aRow[p * 64 + 32 + q8];
    if (isZ1) {  // z1(st+1)
#pragma unroll
      for (int tt = 0; tt < 2; ++tt) {
        floatx4 a0 = biasA[tt];
        a0 = MFMA(wAf[tt][0], bxN, a0);
        a0 = MFMA(wAf[tt][1], bh1a, a0);
        a0 = MFMA(wAf[tt][2], bh1b, a0);
        aB[n264 + (1 - p) * 64 + (w + 8 * tt) * 4 + q] = f2bf(cellUp(a0, cA[tt]));
      }
      const int nx = (st + 2 < TT) ? st + 2 : TT - 1;
      bxN = *(const short8*)&xAll[n968 + nx * 32 + q8];
    } else {     // z2(st)
      const short8 bh2 = *(const short8*)&aRow[128 + (1 - p) * 32 + q8];
#pragma unroll
      for (int tt = 0; tt < 2; ++tt) {
        floatx4 a2 = biasA[tt];
        a2 = MFMA(wAf[tt][0], bh1a, a2);
        a2 = MFMA(wAf[tt][1], bh1b, a2);
        a2 = MFMA(wAf[tt][2], bh2, a2);
        aB[n264 + 128 + p * 32 + (2 * u + tt) * 4 + q] = f2bf(cellUp(a2, cA[tt]));
      }
    }
    __syncthreads();
  };
  for (int st = 0; st < 28; st += 2) { stepA(st, IC<0>{}); stepA(st + 1, IC<1>{}); }
  stepA(28, IC<0>{});
  // ---- tail: z2(29) by z2-waves; h1(29)@64, h2(28)@128 -> latent 160..191 ----
  if (!isZ1) {
    const short8 bh1a = *(const short8*)&aRow[64 + q8];
    const short8 bh1b = *(const short8*)&aRow[96 + q8];
    const short8 bh2  = *(const short8*)&aRow[128 + q8];
#pragma unroll
    for (int tt = 0; tt < 2; ++tt) {
      floatx4 a2 = biasA[tt];
      a2 = MFMA(wAf[tt][0], bh1a, a2);
      a2 = MFMA(wAf[tt][1], bh1b, a2);
      a2 = MFMA(wAf[tt][2], bh2, a2);
      aB[n264 + 160 + (2 * u + tt) * 4 + q] = f2bf(cellUp(a2, cA[tt]));
    }
  }
  __syncthreads();  // latent visible; tail reads of 64..127 done before re-zero below

  // ================= transition: phase-B weights; zero h4(-1) =================
  short8 wBf[2][3]; floatx4 biasB[2];            // z4 (waves 0..7) or z3 (waves 8..11)
  short8 wof[2]; floatx4 biasO;
  short8 blat;
  if (isZ1) {
#pragma unroll
    for (int tt = 0; tt < 2; ++tt) {
      int T = w + 8 * tt;
      int row = ngt * 64 + T * 4 + nlo;
      wBf[tt][0] = ldFragS(&Wih4[row * 32 + q8], sA);
      wBf[tt][1] = ldFragS(&Whh4[row * 64 + q8], sA);
      wBf[tt][2] = ldFragS(&Whh4[row * 64 + 32 + q8], sA);
#pragma unroll
      for (int r = 0; r < 4; ++r) biasB[tt][r] = b4[r * 64 + T * 4 + q] * (r == 2 ? L2 : L1);
    }
    wof[0] = ldFragS(&Wout[n * 64 + q8], 1.f);
    wof[1] = ldFragS(&Wout[n * 64 + 32 + q8], 1.f);
    biasO = *(const floatx4*)&bout[q * 4];
  } else {
#pragma unroll
    for (int tt = 0; tt < 2; ++tt) {
      int T = 2 * u + tt;
      int row = ngt * 32 + T * 4 + nlo;
      wBf[tt][0] = ldFragS(&Wih3[row * 32 + q8], sA);
      wBf[tt][1] = ldFragS(&Whh3[row * 32 + q8], sA);
#pragma unroll
      for (int r = 0; r < 4; ++r) biasB[tt][r] = b3[r * 32 + T * 4 + q] * (r == 2 ? L2 : L1);
    }
    blat = *(const short8*)&aRow[160 + q8];
  }
  for (int i = t; i < 1024; i += NT) aB[(i >> 6) * 264 + 64 + (i & 63)] = 0;  // h4(-1)=0
  __syncthreads();

  float cB[2] = {0.f, 0.f};

  // ---- peel: z3(0) by z3-waves (h3(-1)=0) ----
  if (!isZ1) {
#pragma unroll
    for (int tt = 0; tt < 2; ++tt) {
      floatx4 a3 = biasB[tt];
      a3 = MFMA(wBf[tt][0], blat, a3);
      aB[n264 + 192 + (2 * u + tt) * 4 + q] = f2bf(cellUp(a3, cB[tt]));
    }
  }
  __syncthreads();

  // ================= Phase B: 29 skewed regions, 1 barrier each =================
  auto stepB = [&](int st, auto pc) {
    constexpr int p = decltype(pc)::v;
    const short8 bh3 = *(const short8*)&aRow[192 + p * 32 + q8];
    if (isZ1) {  // z4(st) + rotating proj(st-1)
      const short8 bh4a = *(const short8*)&aRow[(1 - p) * 64 + q8];
      const short8 bh4b = *(const short8*)&aRow[(1 - p) * 64 + 32 + q8];
#pragma unroll
      for (int tt = 0; tt < 2; ++tt) {
        floatx4 a4 = biasB[tt];
        a4 = MFMA(wBf[tt][0], bh3, a4);
        a4 = MFMA(wBf[tt][1], bh4a, a4);
        a4 = MFMA(wBf[tt][2], bh4b, a4);
        aB[n264 + p * 64 + (w + 8 * tt) * 4 + q] = f2bf(cellUp(a4, cB[tt]));
      }
      if (st > 0 && w == ((st - 1) & 7)) {
        floatx4 yv = biasO;
        yv = MFMA(wof[0], bh4a, yv);
        yv = MFMA(wof[1], bh4b, yv);
        *(floatx4*)&out[((size_t)(bBase + n) * TT + (st - 1)) * FF + q * 4] = yv;
      }
    } else {     // z3(st+1)
#pragma unroll
      for (int tt = 0; tt < 2; ++tt) {
        floatx4 a3 = biasB[tt];
        a3 = MFMA(wBf[tt][0], blat, a3);
        a3 = MFMA(wBf[tt][1], bh3, a3);
        aB[n264 + 192 + (1 - p) * 32 + (2 * u + tt) * 4 + q] = f2bf(cellUp(a3, cB[tt]));
      }
    }
    __syncthreads();
  };
  for (int st = 0; st < 28; st += 2) { stepB(st, IC<0>{}); stepB(st + 1, IC<1>{}); }
  stepB(28, IC<0>{});
  // ---- tail: z4(29) (h3(29)@224, h4(28)@0); proj(28); proj(29) ----
  if (isZ1) {
    const short8 bh3  = *(const short8*)&aRow[224 + q8];
    const short8 bh4a = *(const short8*)&aRow[q8];
    const short8 bh4b = *(const short8*)&aRow[32 + q8];
#pragma unroll
    for (int tt = 0; tt < 2; ++tt) {
      floatx4 a4 = biasB[tt];
      a4 = MFMA(wBf[tt][0], bh3, a4);
      a4 = MFMA(wBf[tt][1], bh4a, a4);
      a4 = MFMA(wBf[tt][2], bh4b, a4);
      aB[n264 + 64 + (w + 8 * tt) * 4 + q] = f2bf(cellUp(a4, cB[tt]));
    }
    if (w == 4) {  // proj(28)
      floatx4 yv = biasO;
      yv = MFMA(wof[0], bh4a, yv);
      yv = MFMA(wof[1], bh4b, yv);
      *(floatx4*)&out[((size_t)(bBase + n) * TT + 28) * FF + q * 4] = yv;
    }
  }
  __syncthreads();
  if (w == 5) {  // proj(29): h4(29)@64/96
    const short8 ba = *(const short8*)&aRow[64 + q8];
    const short8 bb = *(const short8*)&aRow[96 + q8];
    floatx4 yv = biasO;
    yv = MFMA(wof[0], ba, yv);
    yv = MFMA(wof[1], bb, yv);
    *(floatx4*)&out[((size_t)(bBase + n) * TT + 29) * FF + q * 4] = yv;
  }
}

extern "C" void kernel_launch(void* const* d_in, const int* in_sizes, int n_in,
                              void* d_out, int out_size, void* d_ws, size_t ws_size,
                              hipStream_t stream) {
  const float* x    = (const float*)d_in[0];
  const float* Wih1 = (const float*)d_in[1];
  const float* Whh1 = (const float*)d_in[2];
  const float* b1   = (const float*)d_in[3];
  const float* Wih2 = (const float*)d_in[4];
  const float* Whh2 = (const float*)d_in[5];
  const float* b2   = (const float*)d_in[6];
  const float* Wih3 = (const float*)d_in[7];
  const float* Whh3 = (const float*)d_in[8];
  const float* b3   = (const float*)d_in[9];
  const float* Wih4 = (const float*)d_in[10];
  const float* Whh4 = (const float*)d_in[11];
  const float* b4   = (const float*)d_in[12];
  const float* Wout = (const float*)d_in[13];
  const float* bout = (const float*)d_in[14];
  float* out = (float*)d_out;

  const int B = in_sizes[0] / (TT * FF);   // 8192
  dim3 grid(B / 16), block(NT);
  lstm_ae_mfma6<<<grid, block, 0, stream>>>(
      x, Wih1, Whh1, b1, Wih2, Whh2, b2, Wih3, Whh3, b3,
      Wih4, Whh4, b4, Wout, bout, out);
}

// Round 9
// 165.704 us; speedup vs baseline: 1.0225x; 1.0225x over previous
//
#include <hip/hip_runtime.h>

// LSTM autoencoder via bf16 MFMA, v7 = v6 + fused sigmoid*tanh (8 trans/cell).
// B=8192, T=30, F=16, H1=64, H2=32. Grid 512 x 768 thr, BT=16, 2 blocks/CU.
// Per step phase A: waves 0..7: z1 tiles {w,w+8}; waves 8..11: z2 tiles {2u,2u+1}.
// Phase B: waves 0..7: z4 {w,w+8} + rotating proj; waves 8..11: z3 {2u,2u+1}.
// log2e folded into weights/biases (gate-g rows x 2log2e); all gates exp2(-acc).
// Fusion: sig(a)*tanh(b) = (1-eb) * rcp((1+ea)*(1+eb)), eb=exp2(-b').
// aB (stride 264 u16): phA h1 dbuf p*64, h2 dbuf 128+p*32, latent 160..191;
//                      phB h4 dbuf p*64, latent 160 (preserved), h3 dbuf 192+p*32.
// LDS: xAll 16x968 (30.2KB) + aB 16x264 (8.25KB) = 38.5KB.

#define TT 30
#define FF 16
#define NT 768

typedef unsigned short u16t;
typedef __attribute__((ext_vector_type(8))) short short8;
typedef __attribute__((ext_vector_type(4))) short short4v;
typedef __attribute__((ext_vector_type(4))) float floatx4;

#define MFMA(a, b, c) __builtin_amdgcn_mfma_f32_16x16x32_bf16(a, b, c, 0, 0, 0)

#if __has_builtin(__builtin_amdgcn_exp2f)
#define EXP2(x) __builtin_amdgcn_exp2f(x)
#else
#define EXP2(x) exp2f(x)
#endif

template <int P> struct IC { static constexpr int v = P; };

__device__ __forceinline__ float rcpf(float v) { return __builtin_amdgcn_rcpf(v); }
__device__ __forceinline__ u16t f2bf(float f) {
  unsigned int u = __float_as_uint(f);
  u = (u + 0x7FFFu + ((u >> 16) & 1u)) >> 16;
  return (u16t)u;
}
__device__ __forceinline__ short8 ldFragS(const float* p, float s) {
  const float4 lo = *(const float4*)p;
  const float4 hi = *(const float4*)(p + 4);
  short8 r;
  r[0] = (short)f2bf(lo.x * s); r[1] = (short)f2bf(lo.y * s);
  r[2] = (short)f2bf(lo.z * s); r[3] = (short)f2bf(lo.w * s);
  r[4] = (short)f2bf(hi.x * s); r[5] = (short)f2bf(hi.y * s);
  r[6] = (short)f2bf(hi.z * s); r[7] = (short)f2bf(hi.w * s);
  return r;
}
// acc pre-scaled: [i,f,o] x log2e, [g] x 2log2e. lane owns i,f,g,o of one unit.
// 5 exp + 3 rcp: fv standalone; i*g and o*tanh(c) fused (one rcp each).
__device__ __forceinline__ float cellUp(const floatx4 acc, float& c) {
  float ei = EXP2(-acc[0]);
  float ef = EXP2(-acc[1]);
  float eg = EXP2(-acc[2]);
  float eo = EXP2(-acc[3]);
  float fv = rcpf(1.f + ef);
  float P  = (1.f - eg) * rcpf((1.f + ei) * (1.f + eg));   // sig(i)*tanh(g)
  c = fv * c + P;
  float ec = EXP2(-2.885390082f * c);
  return (1.f - ec) * rcpf((1.f + eo) * (1.f + ec));       // sig(o)*tanh(c)
}

__global__ __launch_bounds__(NT, 6) void lstm_ae_mfma7(
    const float* __restrict__ x,
    const float* __restrict__ Wih1, const float* __restrict__ Whh1, const float* __restrict__ b1,
    const float* __restrict__ Wih2, const float* __restrict__ Whh2, const float* __restrict__ b2,
    const float* __restrict__ Wih3, const float* __restrict__ Whh3, const float* __restrict__ b3,
    const float* __restrict__ Wih4, const float* __restrict__ Whh4, const float* __restrict__ b4,
    const float* __restrict__ Wout, const float* __restrict__ bout,
    float* __restrict__ out)
{
  __shared__ __align__(16) u16t xAll[16 * 968];  // x bf16, k16..31 zero-pad, stride 968
  __shared__ __align__(16) u16t aB[16 * 264];    // recurrent state, stride 264

  const int t = threadIdx.x;
  const int w = t >> 6, lane = t & 63;           // 12 waves
  const int q = lane >> 4, n = lane & 15;
  const int q8 = q * 8, n264 = n * 264, n968 = n * 968;
  const int bBase = blockIdx.x * 16;
  const int nlo = n >> 2, ngt = n & 3;
  const u16t* aRow = &aB[n264];
  const bool isZ1 = (w < 8);                     // z1/z4 waves vs z2/z3 waves
  const int u = w & 3;                           // for waves 8..11

  const float L1 = 1.442695041f, L2 = 2.885390082f;
  const float sA = (ngt == 2) ? L2 : L1;         // per-lane A-row scale (gate g doubles)

  // ================= init =================
  for (int i = t; i < 16 * 264; i += NT) aB[i] = 0;
  {
    const float* xb = x + (size_t)bBase * (TT * FF);
    for (int i4 = t; i4 < 1920; i4 += NT) {
      int e = i4 * 4;
      int b = e / 480, r = e - b * 480;
      int stp = r >> 4, f = r & 15;
      float4 v = *(const float4*)&xb[e];
      short4v s4 = { (short)f2bf(v.x), (short)f2bf(v.y), (short)f2bf(v.z), (short)f2bf(v.w) };
      *(short4v*)&xAll[b * 968 + stp * 32 + f] = s4;
    }
    for (int i = t; i < 7680; i += NT) {   // zero pads k=16..31
      int b = i / 480, r = i - b * 480;
      int stp = r >> 4, f = r & 15;
      xAll[b * 968 + stp * 32 + 16 + f] = 0;
    }
  }
  const short8 z8 = { 0, 0, 0, 0, 0, 0, 0, 0 };
  short8 wAf[2][3]; floatx4 biasA[2];            // z1 (waves 0..7) or z2 (waves 8..11)
  if (isZ1) {
#pragma unroll
    for (int tt = 0; tt < 2; ++tt) {
      int T = w + 8 * tt;
      int row = ngt * 64 + T * 4 + nlo;
      wAf[tt][0] = z8;
      if (q < 2) wAf[tt][0] = ldFragS(&Wih1[row * 16 + q8], sA);
      wAf[tt][1] = ldFragS(&Whh1[row * 64 + q8], sA);
      wAf[tt][2] = ldFragS(&Whh1[row * 64 + 32 + q8], sA);
#pragma unroll
      for (int r = 0; r < 4; ++r) biasA[tt][r] = b1[r * 64 + T * 4 + q] * (r == 2 ? L2 : L1);
    }
  } else {
#pragma unroll
    for (int tt = 0; tt < 2; ++tt) {
      int T = 2 * u + tt;
      int row = ngt * 32 + T * 4 + nlo;
      wAf[tt][0] = ldFragS(&Wih2[row * 64 + q8], sA);
      wAf[tt][1] = ldFragS(&Wih2[row * 64 + 32 + q8], sA);
      wAf[tt][2] = ldFragS(&Whh2[row * 32 + q8], sA);
#pragma unroll
      for (int r = 0; r < 4; ++r) biasA[tt][r] = b2[r * 32 + T * 4 + q] * (r == 2 ? L2 : L1);
    }
  }
  // anti-phase nudge for likely co-resident pair (i, i+256)
  if (blockIdx.x & 256) {
    __builtin_amdgcn_s_sleep(15);
    __builtin_amdgcn_s_sleep(15);
  }
  __syncthreads();

  float cA[2] = {0.f, 0.f};
  short8 bxN;

  // ---- peel: z1(0) (h1(-1)=0), z2-waves idle ----
  if (isZ1) {
    const short8 bx = *(const short8*)&xAll[n968 + q8];
#pragma unroll
    for (int tt = 0; tt < 2; ++tt) {
      floatx4 a0 = biasA[tt];
      a0 = MFMA(wAf[tt][0], bx, a0);
      aB[n264 + (w + 8 * tt) * 4 + q] = f2bf(cellUp(a0, cA[tt]));
    }
    bxN = *(const short8*)&xAll[n968 + 32 + q8];   // prefetch x(1)
  }
  __syncthreads();

  // ================= Phase A: 29 skewed regions, 1 barrier each =================
  auto stepA = [&](int st, auto pc) {
    constexpr int p = decltype(pc)::v;
    const short8 bh1a = *(const short8*)&aRow[p * 64 + q8];
    const short8 bh1b = *(const short8*)&aRow[p * 64 + 32 + q8];
    if (isZ1) {  // z1(st+1)
#pragma unroll
      for (int tt = 0; tt < 2; ++tt) {
        floatx4 a0 = biasA[tt];
        a0 = MFMA(wAf[tt][0], bxN, a0);
        a0 = MFMA(wAf[tt][1], bh1a, a0);
        a0 = MFMA(wAf[tt][2], bh1b, a0);
        aB[n264 + (1 - p) * 64 + (w + 8 * tt) * 4 + q] = f2bf(cellUp(a0, cA[tt]));
      }
      const int nx = (st + 2 < TT) ? st + 2 : TT - 1;
      bxN = *(const short8*)&xAll[n968 + nx * 32 + q8];
    } else {     // z2(st)
      const short8 bh2 = *(const short8*)&aRow[128 + (1 - p) * 32 + q8];
#pragma unroll
      for (int tt = 0; tt < 2; ++tt) {
        floatx4 a2 = biasA[tt];
        a2 = MFMA(wAf[tt][0], bh1a, a2);
        a2 = MFMA(wAf[tt][1], bh1b, a2);
        a2 = MFMA(wAf[tt][2], bh2, a2);
        aB[n264 + 128 + p * 32 + (2 * u + tt) * 4 + q] = f2bf(cellUp(a2, cA[tt]));
      }
    }
    __syncthreads();
  };
  for (int st = 0; st < 28; st += 2) { stepA(st, IC<0>{}); stepA(st + 1, IC<1>{}); }
  stepA(28, IC<0>{});
  // ---- tail: z2(29) by z2-waves; h1(29)@64, h2(28)@128 -> latent 160..191 ----
  if (!isZ1) {
    const short8 bh1a = *(const short8*)&aRow[64 + q8];
    const short8 bh1b = *(const short8*)&aRow[96 + q8];
    const short8 bh2  = *(const short8*)&aRow[128 + q8];
#pragma unroll
    for (int tt = 0; tt < 2; ++tt) {
      floatx4 a2 = biasA[tt];
      a2 = MFMA(wAf[tt][0], bh1a, a2);
      a2 = MFMA(wAf[tt][1], bh1b, a2);
      a2 = MFMA(wAf[tt][2], bh2, a2);
      aB[n264 + 160 + (2 * u + tt) * 4 + q] = f2bf(cellUp(a2, cA[tt]));
    }
  }
  __syncthreads();  // latent visible; tail reads of 64..127 done before re-zero below

  // ================= transition: phase-B weights; zero h4(-1) =================
  short8 wBf[2][3]; floatx4 biasB[2];            // z4 (waves 0..7) or z3 (waves 8..11)
  short8 wof[2]; floatx4 biasO;
  short8 blat;
  if (isZ1) {
#pragma unroll
    for (int tt = 0; tt < 2; ++tt) {
      int T = w + 8 * tt;
      int row = ngt * 64 + T * 4 + nlo;
      wBf[tt][0] = ldFragS(&Wih4[row * 32 + q8], sA);
      wBf[tt][1] = ldFragS(&Whh4[row * 64 + q8], sA);
      wBf[tt][2] = ldFragS(&Whh4[row * 64 + 32 + q8], sA);
#pragma unroll
      for (int r = 0; r < 4; ++r) biasB[tt][r] = b4[r * 64 + T * 4 + q] * (r == 2 ? L2 : L1);
    }
    wof[0] = ldFragS(&Wout[n * 64 + q8], 1.f);
    wof[1] = ldFragS(&Wout[n * 64 + 32 + q8], 1.f);
    biasO = *(const floatx4*)&bout[q * 4];
  } else {
#pragma unroll
    for (int tt = 0; tt < 2; ++tt) {
      int T = 2 * u + tt;
      int row = ngt * 32 + T * 4 + nlo;
      wBf[tt][0] = ldFragS(&Wih3[row * 32 + q8], sA);
      wBf[tt][1] = ldFragS(&Whh3[row * 32 + q8], sA);
#pragma unroll
      for (int r = 0; r < 4; ++r) biasB[tt][r] = b3[r * 32 + T * 4 + q] * (r == 2 ? L2 : L1);
    }
    blat = *(const short8*)&aRow[160 + q8];
  }
  for (int i = t; i < 1024; i += NT) aB[(i >> 6) * 264 + 64 + (i & 63)] = 0;  // h4(-1)=0
  __syncthreads();

  float cB[2] = {0.f, 0.f};

  // ---- peel: z3(0) by z3-waves (h3(-1)=0) ----
  if (!isZ1) {
#pragma unroll
    for (int tt = 0; tt < 2; ++tt) {
      floatx4 a3 = biasB[tt];
      a3 = MFMA(wBf[tt][0], blat, a3);
      aB[n264 + 192 + (2 * u + tt) * 4 + q] = f2bf(cellUp(a3, cB[tt]));
    }
  }
  __syncthreads();

  // ================= Phase B: 29 skewed regions, 1 barrier each =================
  auto stepB = [&](int st, auto pc) {
    constexpr int p = decltype(pc)::v;
    const short8 bh3 = *(const short8*)&aRow[192 + p * 32 + q8];
    if (isZ1) {  // z4(st) + rotating proj(st-1)
      const short8 bh4a = *(const short8*)&aRow[(1 - p) * 64 + q8];
      const short8 bh4b = *(const short8*)&aRow[(1 - p) * 64 + 32 + q8];
#pragma unroll
      for (int tt = 0; tt < 2; ++tt) {
        floatx4 a4 = biasB[tt];
        a4 = MFMA(wBf[tt][0], bh3, a4);
        a4 = MFMA(wBf[tt][1], bh4a, a4);
        a4 = MFMA(wBf[tt][2], bh4b, a4);
        aB[n264 + p * 64 + (w + 8 * tt) * 4 + q] = f2bf(cellUp(a4, cB[tt]));
      }
      if (st > 0 && w == ((st - 1) & 7)) {
        floatx4 yv = biasO;
        yv = MFMA(wof[0], bh4a, yv);
        yv = MFMA(wof[1], bh4b, yv);
        *(floatx4*)&out[((size_t)(bBase + n) * TT + (st - 1)) * FF + q * 4] = yv;
      }
    } else {     // z3(st+1)
#pragma unroll
      for (int tt = 0; tt < 2; ++tt) {
        floatx4 a3 = biasB[tt];
        a3 = MFMA(wBf[tt][0], blat, a3);
        a3 = MFMA(wBf[tt][1], bh3, a3);
        aB[n264 + 192 + (1 - p) * 32 + (2 * u + tt) * 4 + q] = f2bf(cellUp(a3, cB[tt]));
      }
    }
    __syncthreads();
  };
  for (int st = 0; st < 28; st += 2) { stepB(st, IC<0>{}); stepB(st + 1, IC<1>{}); }
  stepB(28, IC<0>{});
  // ---- tail: z4(29) (h3(29)@224, h4(28)@0); proj(28); proj(29) ----
  if (isZ1) {
    const short8 bh3  = *(const short8*)&aRow[224 + q8];
    const short8 bh4a = *(const short8*)&aRow[q8];
    const short8 bh4b = *(const short8*)&aRow[32 + q8];
#pragma unroll
    for (int tt = 0; tt < 2; ++tt) {
      floatx4 a4 = biasB[tt];
      a4 = MFMA(wBf[tt][0], bh3, a4);
      a4 = MFMA(wBf[tt][1], bh4a, a4);
      a4 = MFMA(wBf[tt][2], bh4b, a4);
      aB[n264 + 64 + (w + 8 * tt) * 4 + q] = f2bf(cellUp(a4, cB[tt]));
    }
    if (w == 4) {  // proj(28)
      floatx4 yv = biasO;
      yv = MFMA(wof[0], bh4a, yv);
      yv = MFMA(wof[1], bh4b, yv);
      *(floatx4*)&out[((size_t)(bBase + n) * TT + 28) * FF + q * 4] = yv;
    }
  }
  __syncthreads();
  if (w == 5) {  // proj(29): h4(29)@64/96
    const short8 ba = *(const short8*)&aRow[64 + q8];
    const short8 bb = *(const short8*)&aRow[96 + q8];
    floatx4 yv = biasO;
    yv = MFMA(wof[0], ba, yv);
    yv = MFMA(wof[1], bb, yv);
    *(floatx4*)&out[((size_t)(bBase + n) * TT + 29) * FF + q * 4] = yv;
  }
}

extern "C" void kernel_launch(void* const* d_in, const int* in_sizes, int n_in,
                              void* d_out, int out_size, void* d_ws, size_t ws_size,
                              hipStream_t stream) {
  const float* x    = (const float*)d_in[0];
  const float* Wih1 = (const float*)d_in[1];
  const float* Whh1 = (const float*)d_in[2];
  const float* b1   = (const float*)d_in[3];
  const float* Wih2 = (const float*)d_in[4];
  const float* Whh2 = (const float*)d_in[5];
  const float* b2   = (const float*)d_in[6];
  const float* Wih3 = (const float*)d_in[7];
  const float* Whh3 = (const float*)d_in[8];
  const float* b3   = (const float*)d_in[9];
  const float* Wih4 = (const float*)d_in[10];
  const float* Whh4 = (const float*)d_in[11];
  const float* b4   = (const float*)d_in[12];
  const float* Wout = (const float*)d_in[13];
  const float* bout = (const float*)d_in[14];
  float* out = (float*)d_out;

  const int B = in_sizes[0] / (TT * FF);   // 8192
  dim3 grid(B / 16), block(NT);
  lstm_ae_mfma7<<<grid, block, 0, stream>>>(
      x, Wih1, Whh1, b1, Wih2, Whh2, b2, Wih3, Whh3, b3,
      Wih4, Whh4, b4, Wout, bout, out);
}

// Round 10
// 158.855 us; speedup vs baseline: 1.0666x; 1.0431x over previous
//
#include <hip/hip_runtime.h>

// LSTM autoencoder via bf16 MFMA, v8: BT=32, one 768-thr block per CU (grid 256).
// Each wave processes TWO batch-halves (n, n+16): 4 independent MFMA+cell chains
// per wave -> 2x ILP at identical per-CU LDS/VALU issue counts vs v7.
// B=8192, T=30, F=16, H1=64, H2=32.
// Per step phase A: waves 0..7: z1 tiles {w,w+8} x2 halves; waves 8..11: z2 x2.
// Phase B: waves 0..7: z4 {w,w+8} x2 + rotating proj x2; waves 8..11: z3 x2.
// log2e folded into weights/biases (gate-g rows x 2log2e); all gates exp2(-acc).
// Fusion: sig(a)*tanh(b) = (1-eb) * rcp((1+ea)*(1+eb)).
// aB (stride 264 u16, 32 rows): phA h1 dbuf p*64, h2 dbuf 128+p*32, latent 160..191;
//                               phB h4 dbuf p*64, latent 160 (preserved), h3 192+p*32.
// LDS: xAll 32x968 (60.5KB) + aB 32x264 (16.5KB) = ~77KB -> 1 block/CU.

#define TT 30
#define FF 16
#define NT 768

typedef unsigned short u16t;
typedef __attribute__((ext_vector_type(8))) short short8;
typedef __attribute__((ext_vector_type(4))) short short4v;
typedef __attribute__((ext_vector_type(4))) float floatx4;

#define MFMA(a, b, c) __builtin_amdgcn_mfma_f32_16x16x32_bf16(a, b, c, 0, 0, 0)

#if __has_builtin(__builtin_amdgcn_exp2f)
#define EXP2(x) __builtin_amdgcn_exp2f(x)
#else
#define EXP2(x) exp2f(x)
#endif

template <int P> struct IC { static constexpr int v = P; };

__device__ __forceinline__ float rcpf(float v) { return __builtin_amdgcn_rcpf(v); }
__device__ __forceinline__ u16t f2bf(float f) {
  unsigned int u = __float_as_uint(f);
  u = (u + 0x7FFFu + ((u >> 16) & 1u)) >> 16;
  return (u16t)u;
}
__device__ __forceinline__ short8 ldFragS(const float* p, float s) {
  const float4 lo = *(const float4*)p;
  const float4 hi = *(const float4*)(p + 4);
  short8 r;
  r[0] = (short)f2bf(lo.x * s); r[1] = (short)f2bf(lo.y * s);
  r[2] = (short)f2bf(lo.z * s); r[3] = (short)f2bf(lo.w * s);
  r[4] = (short)f2bf(hi.x * s); r[5] = (short)f2bf(hi.y * s);
  r[6] = (short)f2bf(hi.z * s); r[7] = (short)f2bf(hi.w * s);
  return r;
}
// acc pre-scaled: [i,f,o] x log2e, [g] x 2log2e. lane owns i,f,g,o of one unit.
__device__ __forceinline__ float cellUp(const floatx4 acc, float& c) {
  float ei = EXP2(-acc[0]);
  float ef = EXP2(-acc[1]);
  float eg = EXP2(-acc[2]);
  float eo = EXP2(-acc[3]);
  float fv = rcpf(1.f + ef);
  float P  = (1.f - eg) * rcpf((1.f + ei) * (1.f + eg));   // sig(i)*tanh(g)
  c = fv * c + P;
  float ec = EXP2(-2.885390082f * c);
  return (1.f - ec) * rcpf((1.f + eo) * (1.f + ec));       // sig(o)*tanh(c)
}

__global__ __launch_bounds__(NT, 3) void lstm_ae_mfma8(
    const float* __restrict__ x,
    const float* __restrict__ Wih1, const float* __restrict__ Whh1, const float* __restrict__ b1,
    const float* __restrict__ Wih2, const float* __restrict__ Whh2, const float* __restrict__ b2,
    const float* __restrict__ Wih3, const float* __restrict__ Whh3, const float* __restrict__ b3,
    const float* __restrict__ Wih4, const float* __restrict__ Whh4, const float* __restrict__ b4,
    const float* __restrict__ Wout, const float* __restrict__ bout,
    float* __restrict__ out)
{
  __shared__ __align__(16) u16t xAll[32 * 968];  // x bf16, k16..31 zero-pad, stride 968
  __shared__ __align__(16) u16t aB[32 * 264];    // recurrent state, stride 264

  const int t = threadIdx.x;
  const int w = t >> 6, lane = t & 63;           // 12 waves
  const int q = lane >> 4, n = lane & 15;
  const int q8 = q * 8;
  const int bBase = blockIdx.x * 32;
  const int nlo = n >> 2, ngt = n & 3;
  const int r0 = n * 264, r1 = (n + 16) * 264;   // two batch-half rows
  const int x0 = n * 968, x1 = (n + 16) * 968;
  const bool isZ1 = (w < 8);
  const int u = w & 3;                           // for waves 8..11

  const float L1 = 1.442695041f, L2 = 2.885390082f;
  const float sA = (ngt == 2) ? L2 : L1;         // gate-g rows scaled 2log2e

  // ================= init =================
  for (int i = t; i < 32 * 264; i += NT) aB[i] = 0;
  {
    const float* xb = x + (size_t)bBase * (TT * FF);
    for (int i4 = t; i4 < 3840; i4 += NT) {
      int e = i4 * 4;
      int b = e / 480, r = e - b * 480;
      int stp = r >> 4, f = r & 15;
      float4 v = *(const float4*)&xb[e];
      short4v s4 = { (short)f2bf(v.x), (short)f2bf(v.y), (short)f2bf(v.z), (short)f2bf(v.w) };
      *(short4v*)&xAll[b * 968 + stp * 32 + f] = s4;
    }
    for (int i = t; i < 15360; i += NT) {   // zero pads k=16..31
      int b = i / 480, r = i - b * 480;
      int stp = r >> 4, f = r & 15;
      xAll[b * 968 + stp * 32 + 16 + f] = 0;
    }
  }
  const short8 z8 = { 0, 0, 0, 0, 0, 0, 0, 0 };
  short8 wAf[2][3]; floatx4 biasA[2];            // z1 (waves 0..7) or z2 (waves 8..11)
  if (isZ1) {
#pragma unroll
    for (int tt = 0; tt < 2; ++tt) {
      int T = w + 8 * tt;
      int row = ngt * 64 + T * 4 + nlo;
      wAf[tt][0] = z8;
      if (q < 2) wAf[tt][0] = ldFragS(&Wih1[row * 16 + q8], sA);
      wAf[tt][1] = ldFragS(&Whh1[row * 64 + q8], sA);
      wAf[tt][2] = ldFragS(&Whh1[row * 64 + 32 + q8], sA);
#pragma unroll
      for (int r = 0; r < 4; ++r) biasA[tt][r] = b1[r * 64 + T * 4 + q] * (r == 2 ? L2 : L1);
    }
  } else {
#pragma unroll
    for (int tt = 0; tt < 2; ++tt) {
      int T = 2 * u + tt;
      int row = ngt * 32 + T * 4 + nlo;
      wAf[tt][0] = ldFragS(&Wih2[row * 64 + q8], sA);
      wAf[tt][1] = ldFragS(&Wih2[row * 64 + 32 + q8], sA);
      wAf[tt][2] = ldFragS(&Whh2[row * 32 + q8], sA);
#pragma unroll
      for (int r = 0; r < 4; ++r) biasA[tt][r] = b2[r * 32 + T * 4 + q] * (r == 2 ? L2 : L1);
    }
  }
  __syncthreads();

  float cA[2][2] = {{0.f, 0.f}, {0.f, 0.f}};     // [half][tile]
  short8 bxN[2];

  // ---- peel: z1(0) (h1(-1)=0) ----
  if (isZ1) {
    const short8 bx0 = *(const short8*)&xAll[x0 + q8];
    const short8 bx1 = *(const short8*)&xAll[x1 + q8];
#pragma unroll
    for (int tt = 0; tt < 2; ++tt) {
      floatx4 a0 = biasA[tt], a1 = biasA[tt];
      a0 = MFMA(wAf[tt][0], bx0, a0);
      a1 = MFMA(wAf[tt][0], bx1, a1);
      aB[r0 + (w + 8 * tt) * 4 + q] = f2bf(cellUp(a0, cA[0][tt]));
      aB[r1 + (w + 8 * tt) * 4 + q] = f2bf(cellUp(a1, cA[1][tt]));
    }
    bxN[0] = *(const short8*)&xAll[x0 + 32 + q8];   // prefetch x(1)
    bxN[1] = *(const short8*)&xAll[x1 + 32 + q8];
  }
  __syncthreads();

  // ================= Phase A: 29 skewed regions, 1 barrier each =================
  auto stepA = [&](int st, auto pc) {
    constexpr int p = decltype(pc)::v;
    const short8 h1a0 = *(const short8*)&aB[r0 + p * 64 + q8];
    const short8 h1b0 = *(const short8*)&aB[r0 + p * 64 + 32 + q8];
    const short8 h1a1 = *(const short8*)&aB[r1 + p * 64 + q8];
    const short8 h1b1 = *(const short8*)&aB[r1 + p * 64 + 32 + q8];
    if (isZ1) {  // z1(st+1) x2 halves
#pragma unroll
      for (int tt = 0; tt < 2; ++tt) {
        floatx4 a0 = biasA[tt], a1 = biasA[tt];
        a0 = MFMA(wAf[tt][0], bxN[0], a0);
        a1 = MFMA(wAf[tt][0], bxN[1], a1);
        a0 = MFMA(wAf[tt][1], h1a0, a0);
        a1 = MFMA(wAf[tt][1], h1a1, a1);
        a0 = MFMA(wAf[tt][2], h1b0, a0);
        a1 = MFMA(wAf[tt][2], h1b1, a1);
        aB[r0 + (1 - p) * 64 + (w + 8 * tt) * 4 + q] = f2bf(cellUp(a0, cA[0][tt]));
        aB[r1 + (1 - p) * 64 + (w + 8 * tt) * 4 + q] = f2bf(cellUp(a1, cA[1][tt]));
      }
      const int nx = (st + 2 < TT) ? st + 2 : TT - 1;
      bxN[0] = *(const short8*)&xAll[x0 + nx * 32 + q8];
      bxN[1] = *(const short8*)&xAll[x1 + nx * 32 + q8];
    } else {     // z2(st) x2 halves
      const short8 h20 = *(const short8*)&aB[r0 + 128 + (1 - p) * 32 + q8];
      const short8 h21 = *(const short8*)&aB[r1 + 128 + (1 - p) * 32 + q8];
#pragma unroll
      for (int tt = 0; tt < 2; ++tt) {
        floatx4 a0 = biasA[tt], a1 = biasA[tt];
        a0 = MFMA(wAf[tt][0], h1a0, a0);
        a1 = MFMA(wAf[tt][0], h1a1, a1);
        a0 = MFMA(wAf[tt][1], h1b0, a0);
        a1 = MFMA(wAf[tt][1], h1b1, a1);
        a0 = MFMA(wAf[tt][2], h20, a0);
        a1 = MFMA(wAf[tt][2], h21, a1);
        aB[r0 + 128 + p * 32 + (2 * u + tt) * 4 + q] = f2bf(cellUp(a0, cA[0][tt]));
        aB[r1 + 128 + p * 32 + (2 * u + tt) * 4 + q] = f2bf(cellUp(a1, cA[1][tt]));
      }
    }
    __syncthreads();
  };
  for (int st = 0; st < 28; st += 2) { stepA(st, IC<0>{}); stepA(st + 1, IC<1>{}); }
  stepA(28, IC<0>{});
  // ---- tail: z2(29); h1(29)@64, h2(28)@128 -> latent 160..191 ----
  if (!isZ1) {
    const short8 h1a0 = *(const short8*)&aB[r0 + 64 + q8];
    const short8 h1b0 = *(const short8*)&aB[r0 + 96 + q8];
    const short8 h1a1 = *(const short8*)&aB[r1 + 64 + q8];
    const short8 h1b1 = *(const short8*)&aB[r1 + 96 + q8];
    const short8 h20  = *(const short8*)&aB[r0 + 128 + q8];
    const short8 h21  = *(const short8*)&aB[r1 + 128 + q8];
#pragma unroll
    for (int tt = 0; tt < 2; ++tt) {
      floatx4 a0 = biasA[tt], a1 = biasA[tt];
      a0 = MFMA(wAf[tt][0], h1a0, a0);
      a1 = MFMA(wAf[tt][0], h1a1, a1);
      a0 = MFMA(wAf[tt][1], h1b0, a0);
      a1 = MFMA(wAf[tt][1], h1b1, a1);
      a0 = MFMA(wAf[tt][2], h20, a0);
      a1 = MFMA(wAf[tt][2], h21, a1);
      aB[r0 + 160 + (2 * u + tt) * 4 + q] = f2bf(cellUp(a0, cA[0][tt]));
      aB[r1 + 160 + (2 * u + tt) * 4 + q] = f2bf(cellUp(a1, cA[1][tt]));
    }
  }
  __syncthreads();

  // ================= transition: phase-B weights; zero h4(-1) =================
  short8 wBf[2][3]; floatx4 biasB[2];
  short8 wof[2]; floatx4 biasO;
  short8 blat[2];
  if (isZ1) {
#pragma unroll
    for (int tt = 0; tt < 2; ++tt) {
      int T = w + 8 * tt;
      int row = ngt * 64 + T * 4 + nlo;
      wBf[tt][0] = ldFragS(&Wih4[row * 32 + q8], sA);
      wBf[tt][1] = ldFragS(&Whh4[row * 64 + q8], sA);
      wBf[tt][2] = ldFragS(&Whh4[row * 64 + 32 + q8], sA);
#pragma unroll
      for (int r = 0; r < 4; ++r) biasB[tt][r] = b4[r * 64 + T * 4 + q] * (r == 2 ? L2 : L1);
    }
    wof[0] = ldFragS(&Wout[n * 64 + q8], 1.f);
    wof[1] = ldFragS(&Wout[n * 64 + 32 + q8], 1.f);
    biasO = *(const floatx4*)&bout[q * 4];
  } else {
#pragma unroll
    for (int tt = 0; tt < 2; ++tt) {
      int T = 2 * u + tt;
      int row = ngt * 32 + T * 4 + nlo;
      wBf[tt][0] = ldFragS(&Wih3[row * 32 + q8], sA);
      wBf[tt][1] = ldFragS(&Whh3[row * 32 + q8], sA);
#pragma unroll
      for (int r = 0; r < 4; ++r) biasB[tt][r] = b3[r * 32 + T * 4 + q] * (r == 2 ? L2 : L1);
    }
    blat[0] = *(const short8*)&aB[r0 + 160 + q8];
    blat[1] = *(const short8*)&aB[r1 + 160 + q8];
  }
  for (int i = t; i < 2048; i += NT) aB[(i >> 6) * 264 + 64 + (i & 63)] = 0;  // h4(-1)=0
  __syncthreads();

  float cB[2][2] = {{0.f, 0.f}, {0.f, 0.f}};

  // ---- peel: z3(0) (h3(-1)=0) ----
  if (!isZ1) {
#pragma unroll
    for (int tt = 0; tt < 2; ++tt) {
      floatx4 a0 = biasB[tt], a1 = biasB[tt];
      a0 = MFMA(wBf[tt][0], blat[0], a0);
      a1 = MFMA(wBf[tt][0], blat[1], a1);
      aB[r0 + 192 + (2 * u + tt) * 4 + q] = f2bf(cellUp(a0, cB[0][tt]));
      aB[r1 + 192 + (2 * u + tt) * 4 + q] = f2bf(cellUp(a1, cB[1][tt]));
    }
  }
  __syncthreads();

  // ================= Phase B: 29 skewed regions, 1 barrier each =================
  auto stepB = [&](int st, auto pc) {
    constexpr int p = decltype(pc)::v;
    const short8 h30 = *(const short8*)&aB[r0 + 192 + p * 32 + q8];
    const short8 h31 = *(const short8*)&aB[r1 + 192 + p * 32 + q8];
    if (isZ1) {  // z4(st) x2 + rotating proj(st-1) x2
      const short8 h4a0 = *(const short8*)&aB[r0 + (1 - p) * 64 + q8];
      const short8 h4b0 = *(const short8*)&aB[r0 + (1 - p) * 64 + 32 + q8];
      const short8 h4a1 = *(const short8*)&aB[r1 + (1 - p) * 64 + q8];
      const short8 h4b1 = *(const short8*)&aB[r1 + (1 - p) * 64 + 32 + q8];
#pragma unroll
      for (int tt = 0; tt < 2; ++tt) {
        floatx4 a0 = biasB[tt], a1 = biasB[tt];
        a0 = MFMA(wBf[tt][0], h30, a0);
        a1 = MFMA(wBf[tt][0], h31, a1);
        a0 = MFMA(wBf[tt][1], h4a0, a0);
        a1 = MFMA(wBf[tt][1], h4a1, a1);
        a0 = MFMA(wBf[tt][2], h4b0, a0);
        a1 = MFMA(wBf[tt][2], h4b1, a1);
        aB[r0 + p * 64 + (w + 8 * tt) * 4 + q] = f2bf(cellUp(a0, cB[0][tt]));
        aB[r1 + p * 64 + (w + 8 * tt) * 4 + q] = f2bf(cellUp(a1, cB[1][tt]));
      }
      if (st > 0 && w == ((st - 1) & 7)) {
        floatx4 y0 = biasO, y1 = biasO;
        y0 = MFMA(wof[0], h4a0, y0);
        y1 = MFMA(wof[0], h4a1, y1);
        y0 = MFMA(wof[1], h4b0, y0);
        y1 = MFMA(wof[1], h4b1, y1);
        *(floatx4*)&out[((size_t)(bBase + n) * TT + (st - 1)) * FF + q * 4] = y0;
        *(floatx4*)&out[((size_t)(bBase + n + 16) * TT + (st - 1)) * FF + q * 4] = y1;
      }
    } else {     // z3(st+1) x2
#pragma unroll
      for (int tt = 0; tt < 2; ++tt) {
        floatx4 a0 = biasB[tt], a1 = biasB[tt];
        a0 = MFMA(wBf[tt][0], blat[0], a0);
        a1 = MFMA(wBf[tt][0], blat[1], a1);
        a0 = MFMA(wBf[tt][1], h30, a0);
        a1 = MFMA(wBf[tt][1], h31, a1);
        aB[r0 + 192 + (1 - p) * 32 + (2 * u + tt) * 4 + q] = f2bf(cellUp(a0, cB[0][tt]));
        aB[r1 + 192 + (1 - p) * 32 + (2 * u + tt) * 4 + q] = f2bf(cellUp(a1, cB[1][tt]));
      }
    }
    __syncthreads();
  };
  for (int st = 0; st < 28; st += 2) { stepB(st, IC<0>{}); stepB(st + 1, IC<1>{}); }
  stepB(28, IC<0>{});
  // ---- tail: z4(29) (h3(29)@224, h4(28)@0); proj(28); proj(29) ----
  if (isZ1) {
    const short8 h30  = *(const short8*)&aB[r0 + 224 + q8];
    const short8 h31  = *(const short8*)&aB[r1 + 224 + q8];
    const short8 h4a0 = *(const short8*)&aB[r0 + q8];
    const short8 h4b0 = *(const short8*)&aB[r0 + 32 + q8];
    const short8 h4a1 = *(const short8*)&aB[r1 + q8];
    const short8 h4b1 = *(const short8*)&aB[r1 + 32 + q8];
#pragma unroll
    for (int tt = 0; tt < 2; ++tt) {
      floatx4 a0 = biasB[tt], a1 = biasB[tt];
      a0 = MFMA(wBf[tt][0], h30, a0);
      a1 = MFMA(wBf[tt][0], h31, a1);
      a0 = MFMA(wBf[tt][1], h4a0, a0);
      a1 = MFMA(wBf[tt][1], h4a1, a1);
      a0 = MFMA(wBf[tt][2], h4b0, a0);
      a1 = MFMA(wBf[tt][2], h4b1, a1);
      aB[r0 + 64 + (w + 8 * tt) * 4 + q] = f2bf(cellUp(a0, cB[0][tt]));
      aB[r1 + 64 + (w + 8 * tt) * 4 + q] = f2bf(cellUp(a1, cB[1][tt]));
    }
    if (w == 4) {  // proj(28)
      floatx4 y0 = biasO, y1 = biasO;
      y0 = MFMA(wof[0], h4a0, y0);
      y1 = MFMA(wof[0], h4a1, y1);
      y0 = MFMA(wof[1], h4b0, y0);
      y1 = MFMA(wof[1], h4b1, y1);
      *(floatx4*)&out[((size_t)(bBase + n) * TT + 28) * FF + q * 4] = y0;
      *(floatx4*)&out[((size_t)(bBase + n + 16) * TT + 28) * FF + q * 4] = y1;
    }
  }
  __syncthreads();
  if (w == 5) {  // proj(29): h4(29)@64/96
    const short8 ba0 = *(const short8*)&aB[r0 + 64 + q8];
    const short8 bb0 = *(const short8*)&aB[r0 + 96 + q8];
    const short8 ba1 = *(const short8*)&aB[r1 + 64 + q8];
    const short8 bb1 = *(const short8*)&aB[r1 + 96 + q8];
    floatx4 y0 = biasO, y1 = biasO;
    y0 = MFMA(wof[0], ba0, y0);
    y1 = MFMA(wof[0], ba1, y1);
    y0 = MFMA(wof[1], bb0, y0);
    y1 = MFMA(wof[1], bb1, y1);
    *(floatx4*)&out[((size_t)(bBase + n) * TT + 29) * FF + q * 4] = y0;
    *(floatx4*)&out[((size_t)(bBase + n + 16) * TT + 29) * FF + q * 4] = y1;
  }
}

extern "C" void kernel_launch(void* const* d_in, const int* in_sizes, int n_in,
                              void* d_out, int out_size, void* d_ws, size_t ws_size,
                              hipStream_t stream) {
  const float* x    = (const float*)d_in[0];
  const float* Wih1 = (const float*)d_in[1];
  const float* Whh1 = (const float*)d_in[2];
  const float* b1   = (const float*)d_in[3];
  const float* Wih2 = (const float*)d_in[4];
  const float* Whh2 = (const float*)d_in[5];
  const float* b2   = (const float*)d_in[6];
  const float* Wih3 = (const float*)d_in[7];
  const float* Whh3 = (const float*)d_in[8];
  const float* b3   = (const float*)d_in[9];
  const float* Wih4 = (const float*)d_in[10];
  const float* Whh4 = (const float*)d_in[11];
  const float* b4   = (const float*)d_in[12];
  const float* Wout = (const float*)d_in[13];
  const float* bout = (const float*)d_in[14];
  float* out = (float*)d_out;

  const int B = in_sizes[0] / (TT * FF);   // 8192
  dim3 grid(B / 32), block(NT);
  lstm_ae_mfma8<<<grid, block, 0, stream>>>(
      x, Wih1, Whh1, b1, Wih2, Whh2, b2, Wih3, Whh3, b3,
      Wih4, Whh4, b4, Wout, bout, out);
}